// Round 1
// baseline (690.537 us; speedup 1.0000x reference)
//
#include <hip/hip_runtime.h>
#include <stdint.h>

#define NB 8
#define NH 96
#define NW_ 96
#define NA 9
#define NANCH (NH * NW_ * NA)   // 82944
#define KPRE 4000
#define MAXOUT 2000
#define KEYCAP 8192
#define WPR 64                  // mask row stride in u64 words (63 used + 1 pad)
#define NWORDS 63               // ceil(4000/64)

// ---------------- Kernel 1: per-batch histogram of score bits ----------------
__global__ void k_hist(const float* __restrict__ score, unsigned* __restrict__ hist) {
    const int b = blockIdx.y;
    __shared__ unsigned h[4096];
    for (int i = threadIdx.x; i < 4096; i += blockDim.x) h[i] = 0u;
    __syncthreads();
    const float* s = score + (size_t)b * NANCH;
    int start = blockIdx.x * blockDim.x + threadIdx.x;
    int stride = gridDim.x * blockDim.x;
    for (int i = start; i < NANCH; i += stride) {
        float v = s[i];
        if (v > 0.5f) {
            unsigned bits = __float_as_uint(v);
            atomicAdd(&h[(bits >> 11) & 4095u], 1u);
        }
    }
    __syncthreads();
    for (int k = threadIdx.x; k < 4096; k += blockDim.x) {
        unsigned c = h[k];
        if (c) atomicAdd(&hist[b * 4096 + k], c);
    }
}

// ---------------- Kernel 2: suffix-sum, find cut bucket, zero counters -------
__global__ void k_cut(const unsigned* __restrict__ hist, unsigned* __restrict__ meta) {
    const int b = blockIdx.x;
    __shared__ unsigned sa[4096];
    __shared__ unsigned sb[4096];
    unsigned* src = sa;
    unsigned* dst = sb;
    for (int k = threadIdx.x; k < 4096; k += blockDim.x) sa[k] = hist[b * 4096 + k];
    __syncthreads();
    for (int d = 1; d < 4096; d <<= 1) {
        for (int k = threadIdx.x; k < 4096; k += blockDim.x)
            dst[k] = src[k] + ((k + d < 4096) ? src[k + d] : 0u);
        __syncthreads();
        unsigned* t = src; src = dst; dst = t;
    }
    if (threadIdx.x == 0) { meta[b] = 0u; meta[8 + b] = 0u; }  // cut default, collect counter = 0
    __syncthreads();
    for (int k = threadIdx.x; k < 4096; k += blockDim.x) {
        unsigned sfx = src[k];
        unsigned nxt = (k + 1 < 4096) ? src[k + 1] : 0u;
        if (sfx >= (unsigned)KPRE && nxt < (unsigned)KPRE) meta[b] = (unsigned)k;
    }
}

// ---------------- Kernel 3: collect candidate keys ---------------------------
__global__ void k_collect(const float* __restrict__ score, unsigned* __restrict__ meta,
                          unsigned long long* __restrict__ keys) {
    const int b = blockIdx.y;
    const unsigned cut = meta[b];
    const float* s = score + (size_t)b * NANCH;
    int start = blockIdx.x * blockDim.x + threadIdx.x;
    int stride = gridDim.x * blockDim.x;
    for (int i = start; i < NANCH; i += stride) {
        float v = s[i];
        if (v > 0.5f) {
            unsigned bits = __float_as_uint(v);
            unsigned bucket = (bits >> 11) & 4095u;
            if (bucket >= cut) {
                unsigned pos = atomicAdd(&meta[8 + b], 1u);
                if (pos < KEYCAP)
                    keys[(size_t)b * KEYCAP + pos] =
                        ((unsigned long long)bits << 32) | (unsigned)(~(unsigned)i);
            }
        }
    }
}

// ---------------- Kernel 4: bitonic sort (desc) + decode top-4000 ------------
__global__ void k_sort_decode(const unsigned long long* __restrict__ keys,
                              unsigned* __restrict__ meta,
                              const float* __restrict__ delta,
                              const float* __restrict__ anchors,
                              float* __restrict__ cand) {
#pragma clang fp contract(off)
    const int b = blockIdx.x;
    __shared__ unsigned long long sk[KEYCAP];   // 64 KiB
    int P = (int)meta[8 + b];
    if (P > KEYCAP) P = KEYCAP;
    for (int i = threadIdx.x; i < KEYCAP; i += blockDim.x)
        sk[i] = (i < P) ? keys[(size_t)b * KEYCAP + i] : 0ull;
    __syncthreads();
    for (int size = 2; size <= KEYCAP; size <<= 1) {
        for (int stride = size >> 1; stride > 0; stride >>= 1) {
            for (int i = threadIdx.x; i < KEYCAP; i += blockDim.x) {
                int j = i ^ stride;
                if (j > i) {
                    unsigned long long a = sk[i], c = sk[j];
                    bool up = ((i & size) == 0);
                    bool sw = up ? (a < c) : (a > c);
                    if (sw) { sk[i] = c; sk[j] = a; }
                }
            }
            __syncthreads();
        }
    }
    int M = P < KPRE ? P : KPRE;
    if (threadIdx.x == 0) meta[16 + b] = (unsigned)M;
    for (int s = threadIdx.x; s < M; s += blockDim.x) {
        unsigned long long key = sk[s];
        int n = (int)(~(unsigned)(key & 0xFFFFFFFFull));
        const float* t = delta + ((size_t)b * NANCH + n) * 4;
        const float* an = anchors + (size_t)n * 4;
        float a0 = an[0], a1 = an[1], a2 = an[2], a3 = an[3];
        float xa = (a0 + a1) * 0.5f;
        float ya = (a2 + a3) * 0.5f;
        float wa = a1 - a0;
        float ha = a3 - a2;
        float tx = t[0], ty = t[1], tw = t[2], th = t[3];
        float x = tx * wa + xa;
        float y = ty * ha + ya;
        float w = expf(tw) * wa;
        float h = expf(th) * ha;
        float xmn = x - w * 0.5f, xmx = x + w * 0.5f;
        float ymn = y - h * 0.5f, ymx = y + h * 0.5f;
        xmn = fminf(fmaxf(xmn, 0.0f), 1.0f);
        xmx = fminf(fmaxf(xmx, 0.0f), 1.0f);
        ymn = fminf(fmaxf(ymn, 0.0f), 1.0f);
        ymx = fminf(fmaxf(ymx, 0.0f), 1.0f);
        float* o = cand + ((size_t)b * KPRE + s) * 4;
        o[0] = xmn; o[1] = xmx; o[2] = ymn; o[3] = ymx;
    }
}

// ---------------- Kernel 5: upper-triangle suppression bit matrix ------------
__global__ void k_mask(const float* __restrict__ cand, unsigned long long* __restrict__ mask) {
#pragma clang fp contract(off)
    const int b = blockIdx.y;
    const int c = blockIdx.x;   // row chunk of 64
    __shared__ float bx[KPRE * 4];  // 64000 B
    {
        const float4* c4 = (const float4*)(cand + (size_t)b * KPRE * 4);
        float4* b4 = (float4*)bx;
        for (int k = threadIdx.x; k < KPRE; k += blockDim.x) b4[k] = c4[k];
    }
    __syncthreads();
    for (int task = threadIdx.x; task < 64 * 64; task += blockDim.x) {
        int ri = task & 63;     // consecutive lanes -> consecutive rows (j-loop broadcasts)
        int w = task >> 6;
        int i = c * 64 + ri;
        if (w >= NWORDS || i >= KPRE) continue;
        unsigned long long bits = 0ull;
        int wi = i >> 6;
        if (w >= wi) {
            float ix0 = bx[i * 4 + 0], ix1 = bx[i * 4 + 1];
            float iy0 = bx[i * 4 + 2], iy1 = bx[i * 4 + 3];
            float ai = (ix1 - ix0) * (iy1 - iy0);
            int j0 = w * 64;
            for (int jj = 0; jj < 64; ++jj) {
                int j = j0 + jj;
                if (j > i && j < KPRE) {
                    float jx0 = bx[j * 4 + 0], jx1 = bx[j * 4 + 1];
                    float jy0 = bx[j * 4 + 2], jy1 = bx[j * 4 + 3];
                    float iw = fminf(ix1, jx1) - fmaxf(ix0, jx0);
                    iw = fmaxf(iw, 0.0f);
                    float ih = fminf(iy1, jy1) - fmaxf(iy0, jy0);
                    ih = fmaxf(ih, 0.0f);
                    float inter = iw * ih;
                    float aj = (jx1 - jx0) * (jy1 - jy0);
                    float uni = ai + aj - inter;
                    float iou = inter / fmaxf(uni, 1e-8f);
                    if (iou > 0.7f) bits |= (1ull << jj);
                }
            }
        }
        mask[((size_t)b * KPRE + i) * WPR + w] = bits;
    }
}

// ---------------- Kernel 6: sequential greedy NMS (one wave per batch) -------
__global__ __launch_bounds__(64) void k_nms(const unsigned long long* __restrict__ mask,
                                            const float* __restrict__ cand,
                                            const unsigned* __restrict__ meta,
                                            float* __restrict__ out) {
    const int b = blockIdx.x;
    const int lane = threadIdx.x;
    const int M = (int)meta[16 + b];
    const unsigned long long* mrow = mask + (size_t)b * KPRE * WPR;
    __shared__ int sel[MAXOUT];
    unsigned long long rem = 0ull;
    int cnt = 0;

#define LDROW(ii) (((ii) < M && lane < NWORDS) ? mrow[(size_t)(ii) * WPR + lane] : 0ull)
#define PROC(mm, ii)                                                      \
    do {                                                                  \
        if ((ii) < M && cnt < MAXOUT) {                                   \
            bool mybit = ((rem >> ((ii) & 63)) & 1ull) != 0ull;           \
            unsigned long long bal = __ballot(mybit);                     \
            if (!((bal >> ((ii) >> 6)) & 1ull)) {                         \
                if (lane == 0) sel[cnt] = (ii);                           \
                cnt++;                                                    \
                rem |= (mm);                                              \
            }                                                             \
        }                                                                 \
    } while (0)

    unsigned long long p0 = LDROW(0), p1 = LDROW(1), p2 = LDROW(2), p3 = LDROW(3);
    unsigned long long p4 = LDROW(4), p5 = LDROW(5), p6 = LDROW(6), p7 = LDROW(7);
    for (int i = 0; i < M && cnt < MAXOUT; i += 8) {
        unsigned long long q0 = LDROW(i + 8), q1 = LDROW(i + 9), q2 = LDROW(i + 10), q3 = LDROW(i + 11);
        unsigned long long q4 = LDROW(i + 12), q5 = LDROW(i + 13), q6 = LDROW(i + 14), q7 = LDROW(i + 15);
        PROC(p0, i + 0); PROC(p1, i + 1); PROC(p2, i + 2); PROC(p3, i + 3);
        PROC(p4, i + 4); PROC(p5, i + 5); PROC(p6, i + 6); PROC(p7, i + 7);
        p0 = q0; p1 = q1; p2 = q2; p3 = q3; p4 = q4; p5 = q5; p6 = q6; p7 = q7;
    }
#undef PROC
#undef LDROW

    __syncthreads();
    const float4* c4 = (const float4*)(cand + (size_t)b * KPRE * 4);
    float4* o4 = (float4*)(out + (size_t)b * MAXOUT * 4);
    for (int r = lane; r < MAXOUT; r += 64) {
        float4 v = make_float4(0.0f, 0.0f, 0.0f, 0.0f);
        if (r < cnt) v = c4[sel[r]];
        o4[r] = v;
    }
}

// ---------------- launch ------------------------------------------------------
extern "C" void kernel_launch(void* const* d_in, const int* in_sizes, int n_in,
                              void* d_out, int out_size, void* d_ws, size_t ws_size,
                              hipStream_t stream) {
    const float* score   = (const float*)d_in[0];
    const float* delta   = (const float*)d_in[1];
    const float* anchors = (const float*)d_in[2];
    float* out = (float*)d_out;

    uint8_t* w8 = (uint8_t*)d_ws;
    // layout (bytes):
    //   hist : [0, 131072)                 8 x 4096 u32
    //   meta : [131072, 132096)            cut[8] | counter[8] | M[8]
    //   keys : [132096, 656384)            8 x 8192 u64
    //   cand : [656384, 1168384)           8 x 4000 x 4 f32
    //   mask : [1168384, 17552384)         8 x 4000 x 64 u64
    unsigned* hist = (unsigned*)(w8 + 0);
    unsigned* meta = (unsigned*)(w8 + 131072);
    unsigned long long* keys = (unsigned long long*)(w8 + 132096);
    float* cand = (float*)(w8 + 656384);
    unsigned long long* mask = (unsigned long long*)(w8 + 1168384);

    hipMemsetAsync(hist, 0, 8 * 4096 * sizeof(unsigned), stream);
    k_hist<<<dim3(8, NB), 256, 0, stream>>>(score, hist);
    k_cut<<<NB, 1024, 0, stream>>>(hist, meta);
    k_collect<<<dim3(32, NB), 256, 0, stream>>>(score, meta, keys);
    k_sort_decode<<<NB, 1024, 0, stream>>>(keys, meta, delta, anchors, cand);
    k_mask<<<dim3((KPRE + 63) / 64, NB), 256, 0, stream>>>(cand, mask);
    k_nms<<<NB, 64, 0, stream>>>(mask, cand, meta, out);
}